// Round 6
// baseline (2987.306 us; speedup 1.0000x reference)
//
#include <hip/hip_runtime.h>
#include <hip/hip_fp16.h>

#define NPTS 262144
#define FDIM 64
#define NCELL 4096   // 16^3 Morton cells
#define NCHUNK 64    // point chunks (4096 pts each) for hist/scatter
#define CPTS 4096
#define TPIX 128     // pixels per transpose tile (48 KB/unit, matches bh unit)
#define GRID 2048    // 256 CU x 8 blocks/CU -- co-resident by __launch_bounds__(256,8)

typedef float vfloat4 __attribute__((ext_vector_type(4)));

// ---------- Morton cell key (16^3) ----------
__device__ __forceinline__ unsigned part4(unsigned v) {
  v &= 15u;
  v = (v | (v << 4)) & 0x0C3u;
  v = (v | (v << 2)) & 0x249u;
  return v;
}

__device__ __forceinline__ unsigned cell_key(float x0, float x1, float x2) {
  const int cx = min(max((int)((x0 + 1.0f) * 8.0f), 0), 15);
  const int cy = min(max((int)((x1 + 1.0f) * 8.0f), 0), 15);
  const int cz = min(max((int)((x2 + 1.0f) * 8.0f), 0), 15);
  return part4((unsigned)cx) | (part4((unsigned)cy) << 1) | (part4((unsigned)cz) << 2);
}

// ---------- device-scope grid barrier (all GRID blocks co-resident) ----------
__device__ __forceinline__ void gridbar(unsigned* bar) {
  __threadfence();  // release: write back this agent's pending stores (cross-XCD)
  __syncthreads();
  if (threadIdx.x == 0) {
    atomicAdd(bar, 1u);
    while (__hip_atomic_load(bar, __ATOMIC_ACQUIRE, __HIP_MEMORY_SCOPE_AGENT) < GRID)
      __builtin_amdgcn_s_sleep(32);
  }
  __syncthreads();
  __threadfence();  // acquire: invalidate stale lines before reading peers' data
}

struct TransposeArgs {
  const float* src[9];
  __half* dst[9];
  int tile_hi[9];  // inclusive prefix sum of tiles per plane; [8] = total tiles
  int SS[9];
};

struct PlanesH { const __half* p[9]; };
struct PlanesF { const float* p[9]; };

union H8 { uint4 u; __half h[8]; };

// ---------- bilinear helpers ----------
__device__ __forceinline__ void bilinear_weights(int W, float cx, float cy,
                                                 float& w00, float& w01, float& w10, float& w11,
                                                 int& xc0, int& xc1, int& yc0, int& yc1) {
  const float Wm1 = (float)(W - 1);
  const float fx = (cx + 1.0f) * 0.5f * Wm1;
  const float fy = (cy + 1.0f) * 0.5f * Wm1;
  const float x0f = floorf(fx), y0f = floorf(fy);
  const float wx = fx - x0f, wy = fy - y0f;
  const int ix = (int)x0f, iy = (int)y0f;
  const int ix1 = ix + 1, iy1 = iy + 1;
  const bool vx0 = (ix >= 0) && (ix < W);
  const bool vx1 = (ix1 >= 0) && (ix1 < W);
  const bool vy0 = (iy >= 0) && (iy < W);
  const bool vy1 = (iy1 >= 0) && (iy1 < W);
  xc0 = min(max(ix, 0), W - 1);
  xc1 = min(max(ix1, 0), W - 1);
  yc0 = min(max(iy, 0), W - 1);
  yc1 = min(max(iy1, 0), W - 1);
  w00 = (1.0f - wx) * (1.0f - wy) * (float)(vx0 && vy0);
  w01 = wx * (1.0f - wy) * (float)(vx1 && vy0);
  w10 = (1.0f - wx) * wy * (float)(vx0 && vy1);
  w11 = wx * wy * (float)(vx1 && vy1);
}

__device__ __forceinline__ void sample8_t(const __half* __restrict__ pl, int W,
                                          float cx, float cy, int j8, float acc[8]) {
  float w00, w01, w10, w11;
  int xc0, xc1, yc0, yc1;
  bilinear_weights(W, cx, cy, w00, w01, w10, w11, xc0, xc1, yc0, yc1);
  const __half* b00 = pl + ((size_t)(yc0 * W + xc0) * FDIM + j8);
  const __half* b01 = pl + ((size_t)(yc0 * W + xc1) * FDIM + j8);
  const __half* b10 = pl + ((size_t)(yc1 * W + xc0) * FDIM + j8);
  const __half* b11 = pl + ((size_t)(yc1 * W + xc1) * FDIM + j8);
  H8 v00, v01, v10, v11;
  v00.u = *(const uint4*)b00;
  v01.u = *(const uint4*)b01;
  v10.u = *(const uint4*)b10;
  v11.u = *(const uint4*)b11;
#pragma unroll
  for (int k = 0; k < 8; ++k) {
    acc[k] += w00 * __half2float(v00.h[k]) + w01 * __half2float(v01.h[k]) +
              w10 * __half2float(v10.h[k]) + w11 * __half2float(v11.h[k]);
  }
}

__device__ __forceinline__ void sample8_d(const float* __restrict__ pl, int W,
                                          float cx, float cy, int j8, float acc[8]) {
  float w00, w01, w10, w11;
  int xc0, xc1, yc0, yc1;
  bilinear_weights(W, cx, cy, w00, w01, w10, w11, xc0, xc1, yc0, yc1);
  const size_t SS = (size_t)W * W;
  const int i00 = yc0 * W + xc0, i01 = yc0 * W + xc1;
  const int i10 = yc1 * W + xc0, i11 = yc1 * W + xc1;
#pragma unroll
  for (int k = 0; k < 8; ++k) {
    const size_t co = (size_t)(j8 + k) * SS;
    acc[k] += w00 * pl[co + i00] + w01 * pl[co + i01] +
              w10 * pl[co + i10] + w11 * pl[co + i11];
  }
}

// ---------- THE mega-kernel: sort + transpose + sample in one dispatch ----------
// ctrl layout (zeroed by one 256 B memset): [0..1]=breaks(inverted max),
// [2]=barA, [3]=barB, [4]=tickA, [5]=tickB
__global__ __launch_bounds__(256, 8) void mega_kernel(const float* __restrict__ x,
                                                      const float* __restrict__ rays_o,
                                                      const float* __restrict__ scale,
                                                      unsigned* __restrict__ ctrl,
                                                      unsigned short* __restrict__ keys,
                                                      unsigned* __restrict__ blockhist,
                                                      unsigned* __restrict__ order,
                                                      TransposeArgs a, PlanesH tp,
                                                      float* __restrict__ out) {
  __shared__ unsigned lh[NCELL];  // 16 KB: hist / scatter bases
  __shared__ unsigned ls[256];    // scan buffer
  __shared__ unsigned uq;         // ticket broadcast
  const int tid = threadIdx.x;
  const float s0 = scale[0], s1 = scale[1], s2 = scale[2];

  // ================= PHASE A: work queue of {64 bh chunks, tiles} =================
  const unsigned nunits = (unsigned)(NCHUNK + a.tile_hi[8]);
  for (;;) {
    if (tid == 0) uq = atomicAdd(&ctrl[4], 1u);
    __syncthreads();
    const unsigned u = uq;
    __syncthreads();
    if (u >= nunits) break;
    if (u < NCHUNK) {
      // ---- break + LDS-private histogram + key cache, points [u*4096, ...) ----
      for (int i = tid; i < NCELL; i += 256) lh[i] = 0u;
      __syncthreads();
      const float r0 = rays_o[0], r1 = rays_o[1], r2 = rays_o[2];
      unsigned m1 = 0u, m2 = 0u;
      const unsigned pb = u * (unsigned)CPTS + (unsigned)tid;
#pragma unroll
      for (int k = 0; k < 16; ++k) {
        const unsigned p = pb + (unsigned)k * 256u;
        const float xs0 = x[p * 3 + 0] * s0;
        const float xs1 = x[p * 3 + 1] * s1;
        const float xs2 = x[p * 3 + 2] * s2;
        const float dx = r0 - xs0;
        const float dy = r1 - xs1;
        const float dz = r2 - xs2;
        const float d = sqrtf(__fadd_rn(__fadd_rn(__fmul_rn(dx, dx), __fmul_rn(dy, dy)),
                                        __fmul_rn(dz, dz)));
        if (d > 1.5f) m1 = max(m1, NPTS - p);  // inverted min-index
        if (d > 2.0f) m2 = max(m2, NPTS - p);
        const unsigned key = cell_key(xs0, xs1, xs2);
        atomicAdd(&lh[key], 1u);
        keys[p] = (unsigned short)key;
      }
#pragma unroll
      for (int o = 32; o > 0; o >>= 1) {
        m1 = max(m1, (unsigned)__shfl_down((int)m1, o, 64));
        m2 = max(m2, (unsigned)__shfl_down((int)m2, o, 64));
      }
      if ((tid & 63) == 0) {
        atomicMax(&ctrl[0], m1);
        atomicMax(&ctrl[1], m2);
      }
      __syncthreads();
      unsigned* bh = blockhist + (size_t)u * NCELL;
      for (int i = tid; i < NCELL; i += 256) bh[i] = lh[i];
    } else {
      // ---- transpose tile: [C][S][S] fp32 -> [S*S][C] fp16, no LDS ----
      const int tile = (int)u - NCHUNK;
      int pi = 0;
#pragma unroll
      for (int i = 0; i < 9; ++i) {
        if (tile >= a.tile_hi[i]) pi = i + 1;
      }
      const int lo = (pi == 0) ? 0 : a.tile_hi[pi - 1];
      const float* __restrict__ src = a.src[pi];
      __half* __restrict__ dst = a.dst[pi];
      const size_t SS = (size_t)a.SS[pi];
      const int slot = tid >> 3;  // 0..31
      const int c8 = tid & 7;     // 0..7
      const size_t p0 = (size_t)(tile - lo) * TPIX + (size_t)slot * 4;
      const float* __restrict__ srcb = src + (size_t)(c8 * 8) * SS + p0;
      H8 h[4];
#pragma unroll
      for (int k = 0; k < 8; ++k) {
        const float4 v = *(const float4*)(srcb + (size_t)k * SS);
        h[0].h[k] = __float2half(v.x);
        h[1].h[k] = __float2half(v.y);
        h[2].h[k] = __float2half(v.z);
        h[3].h[k] = __float2half(v.w);
      }
#pragma unroll
      for (int r = 0; r < 4; ++r) {
        *(uint4*)(dst + (p0 + (size_t)r) * FDIM + c8 * 8) = h[r].u;
      }
    }
    __syncthreads();
  }
  gridbar(&ctrl[2]);

  // ================= PHASE B: 64 scatter units (redundant scan) =================
  for (;;) {
    if (tid == 0) uq = atomicAdd(&ctrl[5], 1u);
    __syncthreads();
    const unsigned u = uq;
    __syncthreads();
    if (u >= NCHUNK) break;
    unsigned tv[16], pv[16];
#pragma unroll
    for (int j = 0; j < 16; ++j) tv[j] = 0u;
#pragma unroll
    for (int j = 0; j < 16; ++j) pv[j] = 0u;
    for (unsigned bp = 0; bp < NCHUNK; ++bp) {
      if (bp == u) {
#pragma unroll
        for (int j = 0; j < 16; ++j) pv[j] = tv[j];
      }
      const uint4* rp = (const uint4*)(blockhist + (size_t)bp * NCELL);
#pragma unroll
      for (int g = 0; g < 4; ++g) {
        const uint4 v = rp[tid * 4 + g];
        tv[g * 4 + 0] += v.x; tv[g * 4 + 1] += v.y;
        tv[g * 4 + 2] += v.z; tv[g * 4 + 3] += v.w;
      }
    }
    unsigned T = 0u;
#pragma unroll
    for (int j = 0; j < 16; ++j) T += tv[j];
    ls[tid] = T;
    __syncthreads();
    for (int d = 1; d < 256; d <<= 1) {
      const unsigned add = (tid >= d) ? ls[tid - d] : 0u;
      __syncthreads();
      ls[tid] += add;
      __syncthreads();
    }
    unsigned running = ls[tid] - T;
    const int c0 = tid * 16;
#pragma unroll
    for (int j = 0; j < 16; ++j) {
      lh[c0 + j] = running + pv[j];
      running += tv[j];
    }
    __syncthreads();
    unsigned b1 = NPTS - ctrl[0]; if (b1 >= NPTS) b1 = 0u;
    unsigned b2 = NPTS - ctrl[1]; if (b2 >= NPTS) b2 = 0u;
    const unsigned pb = u * (unsigned)CPTS + (unsigned)tid;
#pragma unroll
    for (int k = 0; k < 16; ++k) {
      const unsigned p = pb + (unsigned)k * 256u;
      const unsigned key = keys[p];
      const unsigned pos = atomicAdd(&lh[key], 1u);
      const unsigned lvl = (p < b1) ? 0u : ((p < b2) ? 1u : 2u);
      order[pos] = p | (lvl << 18);
    }
    __syncthreads();
  }
  gridbar(&ctrl[3]);

  // ================= PHASE C: sample (grid-stride x4, XCD-contiguous) =========
  const unsigned b = blockIdx.x;
#pragma unroll
  for (int it = 0; it < 4; ++it) {
    const unsigned v = (b & 7u) * 1024u + (unsigned)it * 256u + (b >> 3);
    const int t = (int)(v * 256u + (unsigned)tid);
    const int slot = t >> 3;
    const int j8 = (t & 7) * 8;
    const unsigned pk = order[slot];
    const int p = (int)(pk & 0x3FFFFu);
    const int level = (int)(pk >> 18);
    const float xs0 = x[p * 3 + 0] * s0;
    const float xs1 = x[p * 3 + 1] * s1;
    const float xs2 = x[p * 3 + 2] * s2;
    float acc[8];
#pragma unroll
    for (int k = 0; k < 8; ++k) acc[k] = 0.0f;
    sample8_t(tp.p[0], 512, xs0, xs1, j8, acc);
    sample8_t(tp.p[1], 512, xs1, xs2, j8, acc);
    sample8_t(tp.p[2], 512, xs0, xs2, j8, acc);
    if (level >= 1) {
      sample8_t(tp.p[3], 256, xs0, xs1, j8, acc);
      sample8_t(tp.p[4], 256, xs1, xs2, j8, acc);
      sample8_t(tp.p[5], 256, xs0, xs2, j8, acc);
    }
    if (level >= 2) {
      sample8_t(tp.p[6], 128, xs0, xs1, j8, acc);
      sample8_t(tp.p[7], 128, xs1, xs2, j8, acc);
      sample8_t(tp.p[8], 128, xs0, xs2, j8, acc);
    }
    float* o = out + (size_t)p * FDIM + j8;
    vfloat4 lo4 = {acc[0], acc[1], acc[2], acc[3]};
    vfloat4 hi4 = {acc[4], acc[5], acc[6], acc[7]};
    __builtin_nontemporal_store(lo4, (vfloat4*)o);
    __builtin_nontemporal_store(hi4, (vfloat4*)(o + 4));
  }
}

// ---------- fallback path (ws too small): direct fp32 sampling ----------
__global__ __launch_bounds__(256) void break_kernel(const float* __restrict__ x,
                                                    const float* __restrict__ rays_o,
                                                    const float* __restrict__ scale,
                                                    unsigned* __restrict__ breaks) {
  const unsigned t = blockIdx.x * 256u + threadIdx.x;
  const float r0 = rays_o[0], r1 = rays_o[1], r2 = rays_o[2];
  const float s0 = scale[0], s1 = scale[1], s2 = scale[2];
  unsigned b1 = 0xFFFFFFFFu, b2 = 0xFFFFFFFFu;
  for (unsigned p = t; p < NPTS; p += 65536u) {
    const float dx = r0 - x[p * 3 + 0] * s0;
    const float dy = r1 - x[p * 3 + 1] * s1;
    const float dz = r2 - x[p * 3 + 2] * s2;
    const float d = sqrtf(__fadd_rn(__fadd_rn(__fmul_rn(dx, dx), __fmul_rn(dy, dy)),
                                    __fmul_rn(dz, dz)));
    if (d > 1.5f) b1 = min(b1, p);
    if (d > 2.0f) b2 = min(b2, p);
  }
#pragma unroll
  for (int o = 32; o > 0; o >>= 1) {
    b1 = min(b1, (unsigned)__shfl_down((int)b1, o, 64));
    b2 = min(b2, (unsigned)__shfl_down((int)b2, o, 64));
  }
  if ((threadIdx.x & 63) == 0) {
    atomicMin(&breaks[0], b1);
    atomicMin(&breaks[1], b2);
  }
}

__global__ __launch_bounds__(256) void sample_kernel_direct(const float* __restrict__ x,
                                                            const float* __restrict__ scale,
                                                            const unsigned* __restrict__ breaks,
                                                            PlanesF tp, float* __restrict__ out) {
  const int t = blockIdx.x * 256 + threadIdx.x;
  const int p = t >> 3;
  const int j8 = (t & 7) * 8;
  const float s0 = scale[0], s1 = scale[1], s2 = scale[2];
  const float xs0 = x[p * 3 + 0] * s0;
  const float xs1 = x[p * 3 + 1] * s1;
  const float xs2 = x[p * 3 + 2] * s2;
  unsigned b1 = breaks[0]; if (b1 >= NPTS) b1 = 0;
  unsigned b2 = breaks[1]; if (b2 >= NPTS) b2 = 0;
  const unsigned pu = (unsigned)p;
  const int level = (pu < b1) ? 0 : ((pu < b2) ? 1 : 2);
  float acc[8];
#pragma unroll
  for (int k = 0; k < 8; ++k) acc[k] = 0.0f;
  sample8_d(tp.p[0], 512, xs0, xs1, j8, acc);
  sample8_d(tp.p[1], 512, xs1, xs2, j8, acc);
  sample8_d(tp.p[2], 512, xs0, xs2, j8, acc);
  if (level >= 1) {
    sample8_d(tp.p[3], 256, xs0, xs1, j8, acc);
    sample8_d(tp.p[4], 256, xs1, xs2, j8, acc);
    sample8_d(tp.p[5], 256, xs0, xs2, j8, acc);
  }
  if (level >= 2) {
    sample8_d(tp.p[6], 128, xs0, xs1, j8, acc);
    sample8_d(tp.p[7], 128, xs1, xs2, j8, acc);
    sample8_d(tp.p[8], 128, xs0, xs2, j8, acc);
  }
  float4* o4 = (float4*)(out + (size_t)p * FDIM + j8);
  o4[0] = make_float4(acc[0], acc[1], acc[2], acc[3]);
  o4[1] = make_float4(acc[4], acc[5], acc[6], acc[7]);
}

extern "C" void kernel_launch(void* const* d_in, const int* in_sizes, int n_in,
                              void* d_out, int out_size, void* d_ws, size_t ws_size,
                              hipStream_t stream) {
  const float* x = (const float*)d_in[0];
  const float* rays_o = (const float*)d_in[1];
  const float* scale = (const float*)d_in[2];
  const float* pl32[9];
  for (int i = 0; i < 9; ++i) pl32[i] = (const float*)d_in[3 + i];
  float* out = (float*)d_out;

  unsigned char* ws = (unsigned char*)d_ws;
  // ws: ctrl @0 (256 B, zeroed) | keys @256 (512 KB) | blockhist (1 MB) |
  //     order (1 MB) | planes (~132 MB)
  unsigned* ctrl = (unsigned*)ws;
  unsigned short* keys = (unsigned short*)(ws + 256);
  unsigned* blockhist = (unsigned*)(ws + 256 + (size_t)NPTS * 2);
  unsigned* order = (unsigned*)(ws + 256 + (size_t)NPTS * 2 + (size_t)NCHUNK * NCELL * 4);
  const size_t planes_off = 256 + (size_t)NPTS * 2 + (size_t)NCHUNK * NCELL * 4 + (size_t)NPTS * 4;

  const int Ss[3] = {512, 256, 128};
  size_t need = planes_off;
  for (int l = 0; l < 3; ++l) need += 3 * (size_t)Ss[l] * Ss[l] * FDIM * sizeof(__half);

  if (ws_size >= need) {
    (void)hipMemsetAsync(d_ws, 0, 256, stream);  // breaks + barriers + tickets

    PlanesH tp;
    TransposeArgs ta;
    size_t off = planes_off;
    int tiles_acc = 0;
    for (int l = 0; l < 3; ++l) {
      const int S = Ss[l];
      const int SS = S * S;
      for (int o = 0; o < 3; ++o) {
        const int i = l * 3 + o;
        __half* dst = (__half*)(ws + off);
        tp.p[i] = dst;
        ta.src[i] = pl32[i];
        ta.dst[i] = dst;
        ta.SS[i] = SS;
        tiles_acc += SS / TPIX;
        ta.tile_hi[i] = tiles_acc;
        off += (size_t)SS * FDIM * sizeof(__half);
      }
    }
    mega_kernel<<<GRID, 256, 0, stream>>>(x, rays_o, scale, ctrl, keys, blockhist,
                                          order, ta, tp, out);
  } else {
    (void)hipMemsetAsync(d_ws, 0xFF, 8, stream);
    break_kernel<<<256, 256, 0, stream>>>(x, rays_o, scale, (unsigned*)ws);
    PlanesF tf;
    for (int i = 0; i < 9; ++i) tf.p[i] = pl32[i];
    sample_kernel_direct<<<(NPTS * 8) / 256, 256, 0, stream>>>(x, scale, (unsigned*)ws,
                                                               tf, out);
  }
}

// Round 7
// 408.855 us; speedup vs baseline: 7.3065x; 7.3065x over previous
//
#include <hip/hip_runtime.h>
#include <hip/hip_fp16.h>

#define NPTS 262144
#define FDIM 64
#define NCELL 4096    // 16^3 Morton cells
#define NCHUNK 256    // point chunks (1024 pts each): scatter parallelism
#define CPTS 1024
#define BHPPT 4       // points per thread in bh/scatter (1024/256)

typedef float vfloat4 __attribute__((ext_vector_type(4)));

// ---------- Morton cell key (16^3) ----------
__device__ __forceinline__ unsigned part4(unsigned v) {
  v &= 15u;
  v = (v | (v << 4)) & 0x0C3u;
  v = (v | (v << 2)) & 0x249u;
  return v;
}

__device__ __forceinline__ unsigned cell_key(float x0, float x1, float x2) {
  const int cx = min(max((int)((x0 + 1.0f) * 8.0f), 0), 15);
  const int cy = min(max((int)((x1 + 1.0f) * 8.0f), 0), 15);
  const int cz = min(max((int)((x2 + 1.0f) * 8.0f), 0), 15);
  return part4((unsigned)cx) | (part4((unsigned)cy) << 1) | (part4((unsigned)cz) << 2);
}

// ---------- fused dispatch: [0,NCHUNK) = break+hist blocks, rest = transpose ----------
#define TPIX 128  // pixels per transpose tile

struct TransposeArgs {
  const float* src[9];
  __half* dst[9];
  int tile_hi[9];  // inclusive prefix sum of tiles per plane
  int SS[9];
};

union H8 { uint4 u; __half h[8]; };

__global__ __launch_bounds__(256) void fused_bh_transpose(const float* __restrict__ x,
                                                          const float* __restrict__ rays_o,
                                                          const float* __restrict__ scale,
                                                          unsigned* __restrict__ breaks,
                                                          unsigned short* __restrict__ keys,
                                                          unsigned* __restrict__ blockhist,
                                                          TransposeArgs a) {
  __shared__ unsigned lh[NCELL];  // bh blocks only (16 KB)
  const int bid = blockIdx.x;
  if (bid < NCHUNK) {
    // ---- break + LDS-private histogram + key cache, points [bid*1024, ...) ----
    for (int i = threadIdx.x; i < NCELL; i += 256) lh[i] = 0u;
    __syncthreads();
    const float r0 = rays_o[0], r1 = rays_o[1], r2 = rays_o[2];
    const float s0 = scale[0], s1 = scale[1], s2 = scale[2];
    const unsigned pb = (unsigned)bid * (unsigned)CPTS + threadIdx.x;
    unsigned m1 = 0u, m2 = 0u;
#pragma unroll
    for (int k = 0; k < BHPPT; ++k) {
      const unsigned p = pb + (unsigned)k * 256u;
      const float xs0 = x[p * 3 + 0] * s0;
      const float xs1 = x[p * 3 + 1] * s1;
      const float xs2 = x[p * 3 + 2] * s2;
      const float dx = r0 - xs0;
      const float dy = r1 - xs1;
      const float dz = r2 - xs2;
      const float d = sqrtf(__fadd_rn(__fadd_rn(__fmul_rn(dx, dx), __fmul_rn(dy, dy)),
                                      __fmul_rn(dz, dz)));
      // inverted: max(NPTS - p) over candidates == min index; 0 = no candidate
      if (d > 1.5f) m1 = max(m1, NPTS - p);
      if (d > 2.0f) m2 = max(m2, NPTS - p);
      const unsigned key = cell_key(xs0, xs1, xs2);
      atomicAdd(&lh[key], 1u);  // LDS atomic: CU-local, cheap
      keys[p] = (unsigned short)key;
    }
#pragma unroll
    for (int o = 32; o > 0; o >>= 1) {
      m1 = max(m1, (unsigned)__shfl_down((int)m1, o, 64));
      m2 = max(m2, (unsigned)__shfl_down((int)m2, o, 64));
    }
    if ((threadIdx.x & 63) == 0) {
      atomicMax(&breaks[0], m1);
      atomicMax(&breaks[1], m2);
    }
    __syncthreads();
    unsigned* bh = blockhist + (size_t)bid * NCELL;
    for (int i = threadIdx.x; i < NCELL; i += 256) bh[i] = lh[i];  // coalesced
    return;
  }
  // ---- transpose tile: [C][S][S] fp32 -> [S*S][C] fp16, no LDS ----
  const int tile = bid - NCHUNK;
  int pi = 0;
#pragma unroll
  for (int i = 0; i < 9; ++i) {
    if (tile >= a.tile_hi[i]) pi = i + 1;
  }
  const int lo = (pi == 0) ? 0 : a.tile_hi[pi - 1];
  const float* __restrict__ src = a.src[pi];
  __half* __restrict__ dst = a.dst[pi];
  const size_t SS = (size_t)a.SS[pi];

  const int ntm = (int)(SS / TPIX) - 1;
  const int tl = ((tile - lo) * 997) & ntm;  // bijective tile scatter

  const int t = threadIdx.x;
  const int slot = t >> 3;  // 0..31
  const int c8 = t & 7;     // 0..7
  const size_t p0 = (size_t)tl * TPIX + (size_t)slot * 4;
  const float* __restrict__ srcb = src + (size_t)(c8 * 8) * SS + p0;

  H8 h[4];
#pragma unroll
  for (int k = 0; k < 8; ++k) {
    const float4 v = *(const float4*)(srcb + (size_t)k * SS);
    h[0].h[k] = __float2half(v.x);
    h[1].h[k] = __float2half(v.y);
    h[2].h[k] = __float2half(v.z);
    h[3].h[k] = __float2half(v.w);
  }
#pragma unroll
  for (int r = 0; r < 4; ++r) {
    *(uint4*)(dst + (p0 + (size_t)r) * FDIM + c8 * 8) = h[r].u;
  }
}

// ---------- scan 1: column-parallel exclusive scan along chunks ----------
// Thread c walks cell c's column over all 256 chunk rows (wave reads 256 B
// contiguous per iteration -- fully coalesced), rewriting counts as
// chunk-exclusive prefixes. celltotal[c] = column sum.
__global__ __launch_bounds__(256) void scan_cols_kernel(unsigned* __restrict__ blockhist,
                                                        unsigned* __restrict__ celltotal) {
  const int c = blockIdx.x * 256 + threadIdx.x;  // 16 blocks -> 4096 threads
  unsigned running = 0u;
  for (int b = 0; b < NCHUNK; ++b) {
    unsigned* p = blockhist + (size_t)b * NCELL + c;
    const unsigned v = *p;
    *p = running;
    running += v;
  }
  celltotal[c] = running;
}

// ---------- scan 2: exclusive scan over the 4096 cell totals (in place) ----------
__global__ __launch_bounds__(1024) void scan_cells_kernel(unsigned* __restrict__ celltotal) {
  const int tid = threadIdx.x;  // 1 block x 1024, 4 cells/thread
  uint4 h = ((uint4*)celltotal)[tid];
  const unsigned i0 = h.x;
  const unsigned i1 = i0 + h.y;
  const unsigned i2 = i1 + h.z;
  const unsigned i3 = i2 + h.w;
  __shared__ unsigned ls[1024];
  ls[tid] = i3;
  __syncthreads();
  for (int d = 1; d < 1024; d <<= 1) {
    const unsigned add = (tid >= d) ? ls[tid - d] : 0u;
    __syncthreads();
    ls[tid] += add;
    __syncthreads();
  }
  const unsigned base = ls[tid] - i3;
  uint4 o;
  o.x = base;
  o.y = base + i0;
  o.z = base + i1;
  o.w = base + i2;
  ((uint4*)celltotal)[tid] = o;  // now holds global exclusive cell bases
}

// ---------- scatter: 256 blocks, LDS bases = row + cellbase ----------
__global__ __launch_bounds__(256) void scatter_kernel(const unsigned short* __restrict__ keys,
                                                      const unsigned* __restrict__ breaks,
                                                      const unsigned* __restrict__ blockhist,
                                                      const unsigned* __restrict__ cellbase,
                                                      unsigned* __restrict__ order) {
  __shared__ unsigned lh[NCELL];  // 16 KB
  const unsigned u = blockIdx.x;
  const unsigned* row = blockhist + (size_t)u * NCELL;
  for (int i = threadIdx.x; i < NCELL; i += 256) lh[i] = row[i] + cellbase[i];
  __syncthreads();
  unsigned b1 = NPTS - breaks[0]; if (b1 >= NPTS) b1 = 0u;  // raw=0 -> none -> 0
  unsigned b2 = NPTS - breaks[1]; if (b2 >= NPTS) b2 = 0u;
  const unsigned pb = u * (unsigned)CPTS + threadIdx.x;
#pragma unroll
  for (int k = 0; k < BHPPT; ++k) {
    const unsigned p = pb + (unsigned)k * 256u;
    const unsigned key = keys[p];
    const unsigned pos = atomicAdd(&lh[key], 1u);  // LDS atomic -> exact global slot
    const unsigned lvl = (p < b1) ? 0u : ((p < b2) ? 1u : 2u);
    order[pos] = p | (lvl << 18);  // NPTS = 2^18
  }
}

// ---------- bilinear sampling helpers ----------
__device__ __forceinline__ void bilinear_weights(int W, float cx, float cy,
                                                 float& w00, float& w01, float& w10, float& w11,
                                                 int& xc0, int& xc1, int& yc0, int& yc1) {
  const float Wm1 = (float)(W - 1);
  const float fx = (cx + 1.0f) * 0.5f * Wm1;
  const float fy = (cy + 1.0f) * 0.5f * Wm1;
  const float x0f = floorf(fx), y0f = floorf(fy);
  const float wx = fx - x0f, wy = fy - y0f;
  const int ix = (int)x0f, iy = (int)y0f;
  const int ix1 = ix + 1, iy1 = iy + 1;
  const bool vx0 = (ix >= 0) && (ix < W);
  const bool vx1 = (ix1 >= 0) && (ix1 < W);
  const bool vy0 = (iy >= 0) && (iy < W);
  const bool vy1 = (iy1 >= 0) && (iy1 < W);
  xc0 = min(max(ix, 0), W - 1);
  xc1 = min(max(ix1, 0), W - 1);
  yc0 = min(max(iy, 0), W - 1);
  yc1 = min(max(iy1, 0), W - 1);
  w00 = (1.0f - wx) * (1.0f - wy) * (float)(vx0 && vy0);
  w01 = wx * (1.0f - wy) * (float)(vx1 && vy0);
  w10 = (1.0f - wx) * wy * (float)(vx0 && vy1);
  w11 = wx * wy * (float)(vx1 && vy1);
}

__device__ __forceinline__ void sample8_t(const __half* __restrict__ pl, int W,
                                          float cx, float cy, int j8, float acc[8]) {
  float w00, w01, w10, w11;
  int xc0, xc1, yc0, yc1;
  bilinear_weights(W, cx, cy, w00, w01, w10, w11, xc0, xc1, yc0, yc1);
  const __half* b00 = pl + ((size_t)(yc0 * W + xc0) * FDIM + j8);
  const __half* b01 = pl + ((size_t)(yc0 * W + xc1) * FDIM + j8);
  const __half* b10 = pl + ((size_t)(yc1 * W + xc0) * FDIM + j8);
  const __half* b11 = pl + ((size_t)(yc1 * W + xc1) * FDIM + j8);
  H8 v00, v01, v10, v11;
  v00.u = *(const uint4*)b00;
  v01.u = *(const uint4*)b01;
  v10.u = *(const uint4*)b10;
  v11.u = *(const uint4*)b11;
#pragma unroll
  for (int k = 0; k < 8; ++k) {
    acc[k] += w00 * __half2float(v00.h[k]) + w01 * __half2float(v01.h[k]) +
              w10 * __half2float(v10.h[k]) + w11 * __half2float(v11.h[k]);
  }
}

__device__ __forceinline__ void sample8_d(const float* __restrict__ pl, int W,
                                          float cx, float cy, int j8, float acc[8]) {
  float w00, w01, w10, w11;
  int xc0, xc1, yc0, yc1;
  bilinear_weights(W, cx, cy, w00, w01, w10, w11, xc0, xc1, yc0, yc1);
  const size_t SS = (size_t)W * W;
  const int i00 = yc0 * W + xc0, i01 = yc0 * W + xc1;
  const int i10 = yc1 * W + xc0, i11 = yc1 * W + xc1;
#pragma unroll
  for (int k = 0; k < 8; ++k) {
    const size_t co = (size_t)(j8 + k) * SS;
    acc[k] += w00 * pl[co + i00] + w01 * pl[co + i01] +
              w10 * pl[co + i10] + w11 * pl[co + i11];
  }
}

struct PlanesH { const __half* p[9]; };
struct PlanesF { const float* p[9]; };

// ---------- main sampling kernel (fp16 transposed planes, sorted order) ----------
#define SAMPLE_BLOCKS (NPTS * 8 / 256)  // 8192
#define XCD_CHUNK (SAMPLE_BLOCKS / 8)   // 1024

__global__ __launch_bounds__(256) void sample_kernel(const float* __restrict__ x,
                                                     const float* __restrict__ scale,
                                                     const unsigned* __restrict__ order,
                                                     PlanesH tp, float* __restrict__ out) {
  const unsigned b = blockIdx.x;
  const unsigned sb = (b & 7u) * XCD_CHUNK + (b >> 3);  // XCD-aware bijective swizzle
  const int t = (int)(sb * 256u + threadIdx.x);
  const int slot = t >> 3;
  const int j8 = (t & 7) * 8;
  const unsigned pk = order[slot];  // 4B, broadcast across the point's 8 threads
  const int p = (int)(pk & 0x3FFFFu);
  const int level = (int)(pk >> 18);
  const float s0 = scale[0], s1 = scale[1], s2 = scale[2];
  const float xs0 = x[p * 3 + 0] * s0;  // 3 MB region, cache-resident
  const float xs1 = x[p * 3 + 1] * s1;
  const float xs2 = x[p * 3 + 2] * s2;
  float acc[8];
#pragma unroll
  for (int k = 0; k < 8; ++k) acc[k] = 0.0f;
  sample8_t(tp.p[0], 512, xs0, xs1, j8, acc);  // xy: (x,y)
  sample8_t(tp.p[1], 512, xs1, xs2, j8, acc);  // yz: (y,z)
  sample8_t(tp.p[2], 512, xs0, xs2, j8, acc);  // xz: (x,z)
  if (level >= 1) {
    sample8_t(tp.p[3], 256, xs0, xs1, j8, acc);
    sample8_t(tp.p[4], 256, xs1, xs2, j8, acc);
    sample8_t(tp.p[5], 256, xs0, xs2, j8, acc);
  }
  if (level >= 2) {
    sample8_t(tp.p[6], 128, xs0, xs1, j8, acc);
    sample8_t(tp.p[7], 128, xs1, xs2, j8, acc);
    sample8_t(tp.p[8], 128, xs0, xs2, j8, acc);
  }
  float* o = out + (size_t)p * FDIM + j8;
  vfloat4 lo = {acc[0], acc[1], acc[2], acc[3]};
  vfloat4 hi = {acc[4], acc[5], acc[6], acc[7]};
  __builtin_nontemporal_store(lo, (vfloat4*)o);
  __builtin_nontemporal_store(hi, (vfloat4*)(o + 4));
}

// ---------- fallback path (ws too small) ----------
__global__ __launch_bounds__(256) void break_kernel(const float* __restrict__ x,
                                                    const float* __restrict__ rays_o,
                                                    const float* __restrict__ scale,
                                                    unsigned* __restrict__ breaks) {
  const unsigned t = blockIdx.x * 256u + threadIdx.x;
  const float r0 = rays_o[0], r1 = rays_o[1], r2 = rays_o[2];
  const float s0 = scale[0], s1 = scale[1], s2 = scale[2];
  unsigned b1 = 0xFFFFFFFFu, b2 = 0xFFFFFFFFu;
  for (unsigned p = t; p < NPTS; p += 65536u) {
    const float dx = r0 - x[p * 3 + 0] * s0;
    const float dy = r1 - x[p * 3 + 1] * s1;
    const float dz = r2 - x[p * 3 + 2] * s2;
    const float d = sqrtf(__fadd_rn(__fadd_rn(__fmul_rn(dx, dx), __fmul_rn(dy, dy)),
                                    __fmul_rn(dz, dz)));
    if (d > 1.5f) b1 = min(b1, p);
    if (d > 2.0f) b2 = min(b2, p);
  }
#pragma unroll
  for (int o = 32; o > 0; o >>= 1) {
    b1 = min(b1, (unsigned)__shfl_down((int)b1, o, 64));
    b2 = min(b2, (unsigned)__shfl_down((int)b2, o, 64));
  }
  if ((threadIdx.x & 63) == 0) {
    atomicMin(&breaks[0], b1);
    atomicMin(&breaks[1], b2);
  }
}

__global__ __launch_bounds__(256) void sample_kernel_direct(const float* __restrict__ x,
                                                            const float* __restrict__ scale,
                                                            const unsigned* __restrict__ breaks,
                                                            PlanesF tp, float* __restrict__ out) {
  const int t = blockIdx.x * 256 + threadIdx.x;
  const int p = t >> 3;
  const int j8 = (t & 7) * 8;
  const float s0 = scale[0], s1 = scale[1], s2 = scale[2];
  const float xs0 = x[p * 3 + 0] * s0;
  const float xs1 = x[p * 3 + 1] * s1;
  const float xs2 = x[p * 3 + 2] * s2;
  unsigned b1 = breaks[0]; if (b1 >= NPTS) b1 = 0;
  unsigned b2 = breaks[1]; if (b2 >= NPTS) b2 = 0;
  const unsigned pu = (unsigned)p;
  const int level = (pu < b1) ? 0 : ((pu < b2) ? 1 : 2);
  float acc[8];
#pragma unroll
  for (int k = 0; k < 8; ++k) acc[k] = 0.0f;
  sample8_d(tp.p[0], 512, xs0, xs1, j8, acc);
  sample8_d(tp.p[1], 512, xs1, xs2, j8, acc);
  sample8_d(tp.p[2], 512, xs0, xs2, j8, acc);
  if (level >= 1) {
    sample8_d(tp.p[3], 256, xs0, xs1, j8, acc);
    sample8_d(tp.p[4], 256, xs1, xs2, j8, acc);
    sample8_d(tp.p[5], 256, xs0, xs2, j8, acc);
  }
  if (level >= 2) {
    sample8_d(tp.p[6], 128, xs0, xs1, j8, acc);
    sample8_d(tp.p[7], 128, xs1, xs2, j8, acc);
    sample8_d(tp.p[8], 128, xs0, xs2, j8, acc);
  }
  float4* o4 = (float4*)(out + (size_t)p * FDIM + j8);
  o4[0] = make_float4(acc[0], acc[1], acc[2], acc[3]);
  o4[1] = make_float4(acc[4], acc[5], acc[6], acc[7]);
}

extern "C" void kernel_launch(void* const* d_in, const int* in_sizes, int n_in,
                              void* d_out, int out_size, void* d_ws, size_t ws_size,
                              hipStream_t stream) {
  const float* x = (const float*)d_in[0];
  const float* rays_o = (const float*)d_in[1];
  const float* scale = (const float*)d_in[2];
  const float* pl32[9];
  for (int i = 0; i < 9; ++i) pl32[i] = (const float*)d_in[3 + i];
  float* out = (float*)d_out;

  unsigned char* ws = (unsigned char*)d_ws;
  // ws: breaks @0 (256 B, zeroed) | keys (512 KB) | blockhist (4 MB) |
  //     celltotal (16 KB) | order (1 MB) | planes (~126 MiB)
  unsigned* breaks = (unsigned*)ws;
  unsigned short* keys = (unsigned short*)(ws + 256);
  unsigned* blockhist = (unsigned*)(ws + 256 + (size_t)NPTS * 2);
  unsigned* celltotal = (unsigned*)(ws + 256 + (size_t)NPTS * 2 + (size_t)NCHUNK * NCELL * 4);
  unsigned* order = (unsigned*)(ws + 256 + (size_t)NPTS * 2 + (size_t)NCHUNK * NCELL * 4 +
                                (size_t)NCELL * 4);
  const size_t planes_off = 256 + (size_t)NPTS * 2 + (size_t)NCHUNK * NCELL * 4 +
                            (size_t)NCELL * 4 + (size_t)NPTS * 4;

  const int Ss[3] = {512, 256, 128};
  size_t need = planes_off;
  for (int l = 0; l < 3; ++l) need += 3 * (size_t)Ss[l] * Ss[l] * FDIM * sizeof(__half);

  if (ws_size >= need) {
    (void)hipMemsetAsync(d_ws, 0, 256, stream);  // breaks

    PlanesH tp;
    TransposeArgs ta;
    size_t off = planes_off;
    int tiles_acc = 0;
    for (int l = 0; l < 3; ++l) {
      const int S = Ss[l];
      const int SS = S * S;
      for (int o = 0; o < 3; ++o) {
        const int i = l * 3 + o;
        __half* dst = (__half*)(ws + off);
        tp.p[i] = dst;
        ta.src[i] = pl32[i];
        ta.dst[i] = dst;
        ta.SS[i] = SS;
        tiles_acc += SS / TPIX;
        ta.tile_hi[i] = tiles_acc;
        off += (size_t)SS * FDIM * sizeof(__half);
      }
    }
    fused_bh_transpose<<<NCHUNK + tiles_acc, 256, 0, stream>>>(x, rays_o, scale,
                                                               breaks, keys, blockhist, ta);
    scan_cols_kernel<<<NCELL / 256, 256, 0, stream>>>(blockhist, celltotal);
    scan_cells_kernel<<<1, 1024, 0, stream>>>(celltotal);
    scatter_kernel<<<NCHUNK, 256, 0, stream>>>(keys, breaks, blockhist, celltotal, order);
    sample_kernel<<<SAMPLE_BLOCKS, 256, 0, stream>>>(x, scale, order, tp, out);
  } else {
    (void)hipMemsetAsync(d_ws, 0xFF, 8, stream);
    break_kernel<<<256, 256, 0, stream>>>(x, rays_o, scale, (unsigned*)ws);
    PlanesF tf;
    for (int i = 0; i < 9; ++i) tf.p[i] = pl32[i];
    sample_kernel_direct<<<(NPTS * 8) / 256, 256, 0, stream>>>(x, scale, (unsigned*)ws,
                                                               tf, out);
  }
}